// Round 10
// baseline (263.998 us; speedup 1.0000x reference)
//
#include <hip/hip_runtime.h>
#include <hip/hip_bf16.h>

// Problem constants (B=4, M=4096, DM=1024, H=16, HD=64, SEG=128, DIL=2, BLOCK_M=64)
#define BB 4
#define MM 4096
#define DM 1024
#define NH 16
#define HDIM 64
#define SEGSZ 128
#define NSEG 32
#define ROWS (BB*MM)     // 16384
#define QKVC (3*DM)      // 3072
#define KVROWS (BB*MM/2) // 8192 compact key rows
#define KVLD 2048        // K | V stacked columns
#define NX4  (ROWS*DM/4)     // 4194304
#define NW14 (QKVC*DM/4)     // 786432
#define NW24 (DM*DM/4)       // 262144

typedef __attribute__((ext_vector_type(8))) short bf16x8;
typedef __attribute__((ext_vector_type(4))) float f32x4;

__device__ inline unsigned short f2bf(float f) {
  __hip_bfloat16 h = __float2bfloat16(f);
  return *reinterpret_cast<unsigned short*>(&h);
}

// async global->LDS, 16B per lane; LDS dest = wave-uniform base + lane*16
__device__ __forceinline__ void gld16(const ushort* g, ushort* l) {
  __builtin_amdgcn_global_load_lds(
      (const __attribute__((address_space(1))) unsigned int*)g,
      (__attribute__((address_space(3))) unsigned int*)l,
      16, 0, 0);
}

// ---------------- fused fp32 -> bf16 convert (x | Wqkv | Wout) ----------------
__global__ __launch_bounds__(256) void cvt_all(const float4* __restrict__ x,
                                               const float4* __restrict__ w1,
                                               const float4* __restrict__ w2,
                                               ushort4* __restrict__ xo,
                                               ushort4* __restrict__ w1o,
                                               ushort4* __restrict__ w2o) {
  int i = blockIdx.x * 256 + threadIdx.x;
  const float4* src; ushort4* dst; int off;
  if (i < NX4)              { src = x;  dst = xo;  off = i; }
  else if (i < NX4 + NW14)  { src = w1; dst = w1o; off = i - NX4; }
  else                      { src = w2; dst = w2o; off = i - NX4 - NW14; }
  float4 v = src[off];
  ushort4 o;
  o.x = f2bf(v.x); o.y = f2bf(v.y); o.z = f2bf(v.z); o.w = f2bf(v.w);
  dst[off] = o;
}

// ======================= 256x256 8-phase macro set =======================
// 512 thr = 8 waves (2M x 4N), BM=BN=256, BK=64 in two K-halves.
// LDS 128 KiB: A[db][kh][256][32] bf16 (XOR-swizzled) | B same.
// Per K-tile: PH_F reads af[8]+bfv(CH0) (10 ds_read_b128), MFMAs C-half 0;
// PH_L reads only bfv(CH1) (2 reads), MFMAs C-half 1 reusing af.
//
// ROUND-10 CHANGE: PH_TAIL no longer forces `lgkmcnt(0)` + sched_barrier(0).
// The ds_reads are compiler-visible C++ loads, so hipcc emits counted
// lgkmcnt(N) before each dependent MFMA (m97 behavior) — MFMAs start while
// trailing reads land, instead of a full serial drain per phase (m141:
// order-pinning regression).  Correctness: every ds_read's consuming MFMA
// is in the same phase before barrier-2, so reads are drained before any
// wave's next-phase global_load_lds can overwrite (WAR safe); RAW staging
// is unchanged (counted vmcnt + barrier schedule as verified in r4/r6/r7).
#define STAGE_A(T, KH, DB) do {                                              \
    gld16(pA0 + (T) * 64 + (KH) * 32,                                        \
          sAB + ((DB) * 2 + (KH)) * 8192 + wave * 512);                      \
    gld16(pA1 + (T) * 64 + (KH) * 32,                                        \
          sAB + ((DB) * 2 + (KH)) * 8192 + 4096 + wave * 512);               \
  } while (0)
#define STAGE_B(T, KH, DB) do {                                              \
    gld16(pB0 + (T) * 64 + (KH) * 32,                                        \
          sAB + 32768 + ((DB) * 2 + (KH)) * 8192 + wave * 512);              \
    gld16(pB1 + (T) * 64 + (KH) * 32,                                        \
          sAB + 32768 + ((DB) * 2 + (KH)) * 8192 + 4096 + wave * 512);       \
  } while (0)
#define VM6 asm volatile("s_waitcnt vmcnt(6)" ::: "memory")
#define VM8 asm volatile("s_waitcnt vmcnt(8)" ::: "memory")
#define VM0 asm volatile("s_waitcnt vmcnt(0)" ::: "memory")
#define NOPS ((void)0)

#define PH_TAIL(CH)                                                          \
    __builtin_amdgcn_s_barrier();                                            \
    __builtin_amdgcn_s_setprio(1);                                           \
    _Pragma("unroll")                                                        \
    for (int mf = 0; mf < 8; ++mf)                                           \
      _Pragma("unroll")                                                      \
      for (int nf = 0; nf < 2; ++nf)                                         \
        acc[mf][(CH) * 2 + nf] = __builtin_amdgcn_mfma_f32_16x16x32_bf16(    \
            af[mf], bfv[nf], acc[mf][(CH) * 2 + nf], 0, 0, 0);               \
    __builtin_amdgcn_s_setprio(0);                                           \
    __builtin_amdgcn_s_barrier();

// base-parameterized: full phase (A frags + B half 0) and light phase (B half 1)
#define PH_F_B(AB, BB_, STAGE, VMA) do {                                     \
    const ushort* Ab = (AB); const ushort* Bb = (BB_);                       \
    _Pragma("unroll")                                                        \
    for (int mf = 0; mf < 8; ++mf) {                                         \
      int r = wm * 128 + mf * 16 + m16;                                      \
      af[mf] = *(const bf16x8*)(Ab + r * 32 + ((quad ^ ((r >> 1) & 3)) << 3)); \
    }                                                                        \
    _Pragma("unroll")                                                        \
    for (int nf = 0; nf < 2; ++nf) {                                         \
      int r = wn * 64 + nf * 16 + m16;                                       \
      bfv[nf] = *(const bf16x8*)(Bb + r * 32 + ((quad ^ ((r >> 1) & 3)) << 3)); \
    }                                                                        \
    STAGE; VMA;                                                              \
    PH_TAIL(0)                                                               \
  } while (0)

#define PH_L_B(BB_, STAGE, VMA) do {                                         \
    const ushort* Bb = (BB_);                                                \
    _Pragma("unroll")                                                        \
    for (int nf = 0; nf < 2; ++nf) {                                         \
      int r = wn * 64 + 32 + nf * 16 + m16;                                  \
      bfv[nf] = *(const bf16x8*)(Bb + r * 32 + ((quad ^ ((r >> 1) & 3)) << 3)); \
    }                                                                        \
    STAGE; VMA;                                                              \
    PH_TAIL(1)                                                               \
  } while (0)

#define PH_F(TB, KH, STAGE, VMA) \
    PH_F_B(sAB + ((TB) * 2 + (KH)) * 8192, sAB + 32768 + ((TB) * 2 + (KH)) * 8192, STAGE, VMA)
#define PH_L(TB, KH, STAGE, VMA) \
    PH_L_B(sAB + 32768 + ((TB) * 2 + (KH)) * 8192, STAGE, VMA)

// K-loop over 16 K-tiles (DM=1024), verified schedule: prologue stages 3
// half-tiles (VM8 lands tile0.k0), steady state keeps 3 units in flight
// (VM6 at odd phases), drain waits once (VM0) then 3 stage-free tiles.
#define KLOOP_1024                                                           \
  STAGE_A(0, 0, 0); STAGE_B(0, 0, 0);                                        \
  STAGE_A(0, 1, 0); STAGE_B(0, 1, 0);                                        \
  STAGE_A(1, 0, 1); STAGE_B(1, 0, 1);                                        \
  VM8;                                                                       \
  __builtin_amdgcn_s_barrier();                                              \
  _Pragma("unroll 1")                                                        \
  for (int i = 0; i < 7; ++i) {                                              \
    const int t1 = 2 * i + 1, t2 = 2 * i + 2, t3 = 2 * i + 3;                \
    PH_F(0, 0, STAGE_A(t1, 1, 1), NOPS);                                     \
    PH_L(0, 0, STAGE_B(t1, 1, 1), VM6);                                      \
    PH_F(0, 1, STAGE_A(t2, 0, 0), NOPS);                                     \
    PH_L(0, 1, STAGE_B(t2, 0, 0), VM6);                                      \
    PH_F(1, 0, STAGE_A(t2, 1, 0), NOPS);                                     \
    PH_L(1, 0, STAGE_B(t2, 1, 0), VM6);                                      \
    PH_F(1, 1, STAGE_A(t3, 0, 1), NOPS);                                     \
    PH_L(1, 1, STAGE_B(t3, 0, 1), VM6);                                      \
  }                                                                          \
  PH_F(0, 0, STAGE_A(15, 1, 1), NOPS);                                       \
  PH_L(0, 0, STAGE_B(15, 1, 1), VM0);                                        \
  _Pragma("unroll 1")                                                        \
  for (int u = 1; u < 4; ++u) {                                              \
    const ushort* AbU = sAB + u * 8192;                                      \
    const ushort* BbU = sAB + 32768 + u * 8192;                              \
    PH_F_B(AbU, BbU, NOPS, NOPS);                                            \
    PH_L_B(BbU, NOPS, NOPS);                                                 \
  }

// ---------------- merged Q + KV projection GEMM: 256x256 tiles, 8-phase ----------------
// blocks 0..255:   Q  = x[hilbert rows] @ Wq^T        -> qhb [16384][1024]
// blocks 256..511: KV = x[dilated rows] @ [Wk;Wv]^T   -> kvb [8192][2048]
// XCD-aware bijective swizzle within each 256-block half.
__global__ __launch_bounds__(512) void gemm_qkv(const ushort* __restrict__ xbf,
                                                const ushort* __restrict__ wqkv,
                                                ushort* __restrict__ qhb,
                                                ushort* __restrict__ kvb,
                                                const int* __restrict__ hmap) {
  __shared__ __align__(16) ushort sAB[65536];  // A @0 (4x8192), B @32768 (4x8192)
  __shared__ int sRow[256];

  const int blk = blockIdx.x;
  const int tid = threadIdx.x;
  const int lane = tid & 63;
  const int wave = tid >> 6;
  const int m16 = lane & 15;
  const int quad = lane >> 4;
  const int wm = wave >> 2;   // 0..1  (M half)
  const int wn = wave & 3;    // 0..3  (N quarter)

  const int j0 = blk & 255;
  const int swz = (j0 & 7) * 32 + (j0 >> 3);    // bijective, same-XCD contiguous

  const ushort* Bmat; ushort* C; int row0, col0, N;
  if (blk < 256) {
    row0 = (swz >> 2) * 256; col0 = (swz & 3) * 256;
    Bmat = wqkv; C = qhb; N = DM;
  } else {
    row0 = (swz >> 3) * 256; col0 = (swz & 7) * 256;
    Bmat = wqkv + (size_t)DM * DM; C = kvb; N = KVLD;
  }

  if (tid < 256) {
    int m = row0 + tid, xrow;
    if (blk < 256) {                     // hilbert-ordered Q rows
      int b = m >> 12, p = m & 4095;
      xrow = (b << 12) + hmap[p];
    } else {                             // compact dilated key rows
      int b = m >> 11, idx = m & 2047;
      int ss = idx >> 6, tt = idx & 63;
      xrow = (b << 12) + hmap[ss * SEGSZ + 2 * tt];
    }
    sRow[tid] = xrow;
  }
  __syncthreads();

  // staging: flat 16B chunk f within a unit; row = f>>2, swizzled col slot =
  // (f&3) ^ ((f>>3)&3).  Involution; read side applies the same XOR.
  const int f0 = wave * 64 + lane, f1 = 512 + f0;
  const int r0 = f0 >> 2, c0 = (f0 & 3) ^ ((f0 >> 3) & 3);
  const int r1 = f1 >> 2, c1 = (f1 & 3) ^ ((f1 >> 3) & 3);
  const ushort* pA0 = xbf + (size_t)sRow[r0] * DM + c0 * 8;
  const ushort* pA1 = xbf + (size_t)sRow[r1] * DM + c1 * 8;
  const ushort* pB0 = Bmat + (size_t)(col0 + r0) * DM + c0 * 8;
  const ushort* pB1 = Bmat + (size_t)(col0 + r1) * DM + c1 * 8;

  f32x4 acc[8][4] = {};
  bf16x8 af[8], bfv[2];

  KLOOP_1024

  // C/D layout: col = lane&15, row = (lane>>4)*4 + r
#pragma unroll
  for (int mf = 0; mf < 8; ++mf)
#pragma unroll
    for (int rr = 0; rr < 4; ++rr) {
      int row = row0 + wm * 128 + mf * 16 + quad * 4 + rr;
#pragma unroll
      for (int nf = 0; nf < 4; ++nf)
        C[(size_t)row * N + col0 + wn * 64 + nf * 16 + m16] = f2bf(acc[mf][nf][rr]);
    }
}

// ---------------- out-projection GEMM: 256x256 tiles, 8-phase, fp32 out ----------------
// out[m][n] = sum_k attn[m,k] * Wout[n,k];  grid 256 = 64 row-tiles x 4 col-tiles.
__global__ __launch_bounds__(512) void gemm_out(const ushort* __restrict__ A,
                                                const ushort* __restrict__ Bmat,
                                                float* __restrict__ C) {
  __shared__ __align__(16) ushort sAB[65536];

  const int tid = threadIdx.x;
  const int lane = tid & 63;
  const int wave = tid >> 6;
  const int m16 = lane & 15;
  const int quad = lane >> 4;
  const int wm = wave >> 2;
  const int wn = wave & 3;

  const int j0 = blockIdx.x;
  const int swz = (j0 & 7) * 32 + (j0 >> 3);    // XCD swizzle
  const int row0 = (swz >> 2) * 256;
  const int col0 = (swz & 3) * 256;

  const int f0 = wave * 64 + lane, f1 = 512 + f0;
  const int r0 = f0 >> 2, c0 = (f0 & 3) ^ ((f0 >> 3) & 3);
  const int r1 = f1 >> 2, c1 = (f1 & 3) ^ ((f1 >> 3) & 3);
  const ushort* pA0 = A + (size_t)(row0 + r0) * DM + c0 * 8;
  const ushort* pA1 = A + (size_t)(row0 + r1) * DM + c1 * 8;
  const ushort* pB0 = Bmat + (size_t)(col0 + r0) * DM + c0 * 8;
  const ushort* pB1 = Bmat + (size_t)(col0 + r1) * DM + c1 * 8;

  f32x4 acc[8][4] = {};
  bf16x8 af[8], bfv[2];

  KLOOP_1024

#pragma unroll
  for (int mf = 0; mf < 8; ++mf)
#pragma unroll
    for (int rr = 0; rr < 4; ++rr) {
      int row = row0 + wm * 128 + mf * 16 + quad * 4 + rr;
#pragma unroll
      for (int nf = 0; nf < 4; ++nf)
        C[(size_t)row * DM + col0 + wn * 64 + nf * 16 + m16] = acc[mf][nf][rr];
    }
}

#undef KLOOP_1024
#undef PH_F
#undef PH_L
#undef PH_F_B
#undef PH_L_B
#undef PH_TAIL
#undef STAGE_A
#undef STAGE_B
#undef VM6
#undef VM8
#undef VM0
#undef NOPS

// ---------------- fused hilbert attention (compact inputs, MFMA) ----------------
// one workgroup (256 thr = 4 waves) per (b,h,s): 128 queries x 64 dilated keys.
__global__ __launch_bounds__(256) void attn_kernel(const ushort* __restrict__ qh,
                                                   const ushort* __restrict__ kv,
                                                   ushort* __restrict__ out) {
  __shared__ __align__(16) ushort sQW[128 * 72];  // Q [q][d]; reused for W [q][t]
  __shared__ __align__(16) ushort sK[64 * 72];    // [t][d]
  __shared__ __align__(16) ushort sVT[64 * 72];   // [d][t]
  __shared__ float sCmaxW[4 * 64];
  __shared__ float sDen[128];

  const int bid = blockIdx.x;
  const int s  = bid & 31;
  const int h  = (bid >> 5) & 15;
  const int b  = bid >> 9;
  const int tid = threadIdx.x;
  const int lane = tid & 63;
  const int wave = tid >> 6;
  const int m16 = lane & 15;
  const int quad = lane >> 4;
  const int qb = wave * 32;
  const int hb = wave >> 1;

  // ---- stage Q (128 rows), K + V^T (64 rows) — all coalesced ----
  {
    const int qr = tid >> 1;
    const int qc = (tid & 1) * 32;
    const ushort* qrow = qh + (size_t)(b * MM + s * SEGSZ + qr) * DM + h * HDIM + qc;
    *(uint4*)(sQW + qr * 72 + qc)      = ((const uint4*)qrow)[0];
    *(uint4*)(sQW + qr * 72 + qc + 8)  = ((const uint4*)qrow)[1];
    *(uint4*)(sQW + qr * 72 + qc + 16) = ((const uint4*)qrow)[2];
    *(uint4*)(sQW + qr * 72 + qc + 24) = ((const uint4*)qrow)[3];

    const int r = tid >> 2;
    const int c = (tid & 3) * 16;
    const ushort* krow = kv + (size_t)(b * (MM/2) + s * 64 + r) * KVLD + h * HDIM + c;
    const ushort* vrow = krow + DM;
    *(uint4*)(sK + r * 72 + c)     = ((const uint4*)krow)[0];
    *(uint4*)(sK + r * 72 + c + 8) = ((const uint4*)krow)[1];
    ushort vv[16];
    *(uint4*)(vv)     = ((const uint4*)vrow)[0];
    *(uint4*)(vv + 8) = ((const uint4*)vrow)[1];
#pragma unroll
    for (int u = 0; u < 16; ++u) sVT[(c + u) * 72 + r] = vv[u];
  }
  __syncthreads();

  // ---- S = (Q K^T) * SCALE ----
  f32x4 sc[2][4];
  {
    bf16x8 aq[2][2], bk[4][2];
#pragma unroll
    for (int ks = 0; ks < 2; ++ks) {
#pragma unroll
      for (int ib = 0; ib < 2; ++ib)
        aq[ib][ks] = *(const bf16x8*)(sQW + (qb + ib * 16 + m16) * 72 + ks * 32 + quad * 8);
#pragma unroll
      for (int j = 0; j < 4; ++j)
        bk[j][ks] = *(const bf16x8*)(sK + (j * 16 + m16) * 72 + ks * 32 + quad * 8);
    }
#pragma unroll
    for (int ib = 0; ib < 2; ++ib)
#pragma unroll
      for (int j = 0; j < 4; ++j) {
        f32x4 a = {};
        a = __builtin_amdgcn_mfma_f32_16x16x32_bf16(aq[ib][0], bk[j][0], a, 0, 0, 0);
        a = __builtin_amdgcn_mfma_f32_16x16x32_bf16(aq[ib][1], bk[j][1], a, 0, 0, 0);
        sc[ib][j] = a * 0.125f;
      }
  }

  // ---- per-key max per 64-query block (faithful quirk) ----
#pragma unroll
  for (int j = 0; j < 4; ++j) {
    float m = -1e30f;
#pragma unroll
    for (int ib = 0; ib < 2; ++ib)
#pragma unroll
      for (int r = 0; r < 4; ++r) m = fmaxf(m, sc[ib][j][r]);
    m = fmaxf(m, __shfl_xor(m, 16));
    m = fmaxf(m, __shfl_xor(m, 32));
    if (quad == 0) sCmaxW[wave * 64 + j * 16 + m16] = m;
  }
  __syncthreads();

  // ---- w = exp(s - c); per-row sums; W -> LDS (alias over dead Q) ----
  {
    float part[2][4] = {};
#pragma unroll
    for (int j = 0; j < 4; ++j) {
      const int col = j * 16 + m16;
      float c0 = fmaxf(sCmaxW[hb * 128 + col], sCmaxW[hb * 128 + 64 + col]);
#pragma unroll
      for (int ib = 0; ib < 2; ++ib)
#pragma unroll
        for (int r = 0; r < 4; ++r) {
          float ww = __expf(sc[ib][j][r] - c0);
          sc[ib][j][r] = ww;
          part[ib][r] += ww;
        }
    }
#pragma unroll
    for (int ib = 0; ib < 2; ++ib)
#pragma unroll
      for (int r = 0; r < 4; ++r) {
        float p = part[ib][r];
        p += __shfl_xor(p, 1); p += __shfl_xor(p, 2);
        p += __shfl_xor(p, 4); p += __shfl_xor(p, 8);
        if (m16 == 0) sDen[qb + ib * 16 + quad * 4 + r] = p;
      }
#pragma unroll
    for (int ib = 0; ib < 2; ++ib)
#pragma unroll
      for (int j = 0; j < 4; ++j)
#pragma unroll
        for (int r = 0; r < 4; ++r)
          sQW[(qb + ib * 16 + quad * 4 + r) * 72 + j * 16 + m16] = f2bf(sc[ib][j][r]);
  }
  __syncthreads();

  // ---- O = W @ V via MFMA ----
  f32x4 o[2][4] = {};
  {
    bf16x8 aw[2][2], bv[4][2];
#pragma unroll
    for (int ks = 0; ks < 2; ++ks) {
#pragma unroll
      for (int ib = 0; ib < 2; ++ib)
        aw[ib][ks] = *(const bf16x8*)(sQW + (qb + ib * 16 + m16) * 72 + ks * 32 + quad * 8);
#pragma unroll
      for (int j = 0; j < 4; ++j)
        bv[j][ks] = *(const bf16x8*)(sVT + (j * 16 + m16) * 72 + ks * 32 + quad * 8);
    }
#pragma unroll
    for (int ib = 0; ib < 2; ++ib)
#pragma unroll
      for (int j = 0; j < 4; ++j) {
        o[ib][j] = __builtin_amdgcn_mfma_f32_16x16x32_bf16(aw[ib][0], bv[j][0], o[ib][j], 0, 0, 0);
        o[ib][j] = __builtin_amdgcn_mfma_f32_16x16x32_bf16(aw[ib][1], bv[j][1], o[ib][j], 0, 0, 0);
      }
  }

  // ---- divide by den, store at LINEAR positions ----
#pragma unroll
  for (int ib = 0; ib < 2; ++ib)
#pragma unroll
    for (int r = 0; r < 4; ++r) {
      const int lrow = qb + ib * 16 + quad * 4 + r;
      float rd = 1.0f / (1e-10f + sDen[lrow]);
      ushort* op = out + (size_t)(b * MM + s * SEGSZ + lrow) * DM + h * HDIM + m16;
#pragma unroll
      for (int j = 0; j < 4; ++j)
        op[j * 16] = f2bf(o[ib][j][r] * rd);
    }
}

// ---------------- launch ----------------
extern "C" void kernel_launch(void* const* d_in, const int* in_sizes, int n_in,
                              void* d_out, int out_size, void* d_ws, size_t ws_size,
                              hipStream_t stream) {
  const float* x    = (const float*)d_in[0];
  const float* wqkv = (const float*)d_in[1];
  const float* wout = (const float*)d_in[2];
  const int*   hmap = (const int*)d_in[3];
  float* outp = (float*)d_out;

  ushort* xbf    = (ushort*)d_ws;                          // ROWS*DM
  ushort* wqkvbf = xbf + (size_t)ROWS * DM;                // QKVC*DM
  ushort* woutbf = wqkvbf + (size_t)QKVC * DM;             // DM*DM
  ushort* qhb    = woutbf + (size_t)DM * DM;               // ROWS*DM (hilbert-ordered Q)
  ushort* kvb    = qhb + (size_t)ROWS * DM;                // KVROWS*KVLD (compact K|V)
  ushort* attn   = kvb + (size_t)KVROWS * KVLD;            // ROWS*DM

  cvt_all<<<(NX4 + NW14 + NW24 + 255) / 256, 256, 0, stream>>>(
      (const float4*)x, (const float4*)wqkv, (const float4*)wout,
      (ushort4*)xbf, (ushort4*)wqkvbf, (ushort4*)woutbf);

  // Q + KV projections in one dispatch (512 blocks x 512 thr, 256^2 8-phase)
  gemm_qkv<<<512, 512, 0, stream>>>(xbf, wqkvbf, qhb, kvb, hmap);

  // fused hilbert attention (compact, coalesced)
  attn_kernel<<<BB * NH * NSEG, 256, 0, stream>>>(qhb, kvb, attn);

  // out = attn @ Wout^T (fp32 out, 256^2 8-phase, 256 blocks, XCD swizzle)
  gemm_out<<<256, 512, 0, stream>>>(attn, woutbf, outp);
}

// Round 11
// 254.089 us; speedup vs baseline: 1.0390x; 1.0390x over previous
//
#include <hip/hip_runtime.h>
#include <hip/hip_bf16.h>

// Problem constants (B=4, M=4096, DM=1024, H=16, HD=64, SEG=128, DIL=2, BLOCK_M=64)
#define BB 4
#define MM 4096
#define DM 1024
#define NH 16
#define HDIM 64
#define SEGSZ 128
#define NSEG 32
#define ROWS (BB*MM)     // 16384
#define QKVC (3*DM)      // 3072
#define KVROWS (BB*MM/2) // 8192 compact key rows
#define KVLD 2048        // K | V stacked columns
#define NX4  (ROWS*DM/4)     // 4194304
#define NW14 (QKVC*DM/4)     // 786432
#define NW24 (DM*DM/4)       // 262144

typedef __attribute__((ext_vector_type(8))) short bf16x8;
typedef __attribute__((ext_vector_type(4))) float f32x4;

__device__ inline unsigned short f2bf(float f) {
  __hip_bfloat16 h = __float2bfloat16(f);
  return *reinterpret_cast<unsigned short*>(&h);
}

// async global->LDS, 16B per lane; LDS dest = wave-uniform base + lane*16
__device__ __forceinline__ void gld16(const ushort* g, ushort* l) {
  __builtin_amdgcn_global_load_lds(
      (const __attribute__((address_space(1))) unsigned int*)g,
      (__attribute__((address_space(3))) unsigned int*)l,
      16, 0, 0);
}

// ---------------- fused fp32 -> bf16 convert (x | Wqkv | Wout) ----------------
__global__ __launch_bounds__(256) void cvt_all(const float4* __restrict__ x,
                                               const float4* __restrict__ w1,
                                               const float4* __restrict__ w2,
                                               ushort4* __restrict__ xo,
                                               ushort4* __restrict__ w1o,
                                               ushort4* __restrict__ w2o) {
  int i = blockIdx.x * 256 + threadIdx.x;
  const float4* src; ushort4* dst; int off;
  if (i < NX4)              { src = x;  dst = xo;  off = i; }
  else if (i < NX4 + NW14)  { src = w1; dst = w1o; off = i - NX4; }
  else                      { src = w2; dst = w2o; off = i - NX4 - NW14; }
  float4 v = src[off];
  ushort4 o;
  o.x = f2bf(v.x); o.y = f2bf(v.y); o.z = f2bf(v.z); o.w = f2bf(v.w);
  dst[off] = o;
}

// ======================= 256x256 8-phase macro set =======================
// 512 thr = 8 waves (2M x 4N), BM=BN=256, BK=64 in two K-halves.
// LDS 128 KiB: A[db][kh][256][32] bf16 (XOR-swizzled) | B same.
// Per K-tile: PH_F reads af[8]+bfv(CH0) (10 ds_read_b128), MFMAs C-half 0;
// PH_L reads only bfv(CH1) (2 reads), MFMAs C-half 1 reusing af.
//
// ROUND-11 CHANGE: ONE barrier per phase (deleted trailing s_barrier).
// r10 proved the lgkm drain was not the stall; the 2-barrier envelope was:
// barrier-2 forced strict alternation of [all-waves LDS burst] and
// [all-waves MFMA], so PH_F's ~960cyc read service never hid under the
// ~620cyc MFMA.  With one barrier/phase waves slip within the phase —
// one wave's MFMA overlaps another's reads — and barrier count halves.
// Hazard ledger: WAR — stage(X,p) issues after barrier(p-1); all waves'
// reads(X,p-2) are register-consumed (compiler lgkm) before they reach
// barrier(p-1).  RAW — every wave's vmcnt precedes its barrier; dependent
// reads issue only after that barrier, so "all-waves vmcnt -> barrier ->
// read" is preserved (prologue VM8 and drain VM0 re-checked).
#define STAGE_A(T, KH, DB) do {                                              \
    gld16(pA0 + (T) * 64 + (KH) * 32,                                        \
          sAB + ((DB) * 2 + (KH)) * 8192 + wave * 512);                      \
    gld16(pA1 + (T) * 64 + (KH) * 32,                                        \
          sAB + ((DB) * 2 + (KH)) * 8192 + 4096 + wave * 512);               \
  } while (0)
#define STAGE_B(T, KH, DB) do {                                              \
    gld16(pB0 + (T) * 64 + (KH) * 32,                                        \
          sAB + 32768 + ((DB) * 2 + (KH)) * 8192 + wave * 512);              \
    gld16(pB1 + (T) * 64 + (KH) * 32,                                        \
          sAB + 32768 + ((DB) * 2 + (KH)) * 8192 + 4096 + wave * 512);       \
  } while (0)
#define VM6 asm volatile("s_waitcnt vmcnt(6)" ::: "memory")
#define VM8 asm volatile("s_waitcnt vmcnt(8)" ::: "memory")
#define VM0 asm volatile("s_waitcnt vmcnt(0)" ::: "memory")
#define NOPS ((void)0)

#define PH_TAIL(CH)                                                          \
    __builtin_amdgcn_s_barrier();                                            \
    __builtin_amdgcn_s_setprio(1);                                           \
    _Pragma("unroll")                                                        \
    for (int mf = 0; mf < 8; ++mf)                                           \
      _Pragma("unroll")                                                      \
      for (int nf = 0; nf < 2; ++nf)                                         \
        acc[mf][(CH) * 2 + nf] = __builtin_amdgcn_mfma_f32_16x16x32_bf16(    \
            af[mf], bfv[nf], acc[mf][(CH) * 2 + nf], 0, 0, 0);               \
    __builtin_amdgcn_s_setprio(0);

// base-parameterized: full phase (A frags + B half 0) and light phase (B half 1)
#define PH_F_B(AB, BB_, STAGE, VMA) do {                                     \
    const ushort* Ab = (AB); const ushort* Bb = (BB_);                       \
    _Pragma("unroll")                                                        \
    for (int mf = 0; mf < 8; ++mf) {                                         \
      int r = wm * 128 + mf * 16 + m16;                                      \
      af[mf] = *(const bf16x8*)(Ab + r * 32 + ((quad ^ ((r >> 1) & 3)) << 3)); \
    }                                                                        \
    _Pragma("unroll")                                                        \
    for (int nf = 0; nf < 2; ++nf) {                                         \
      int r = wn * 64 + nf * 16 + m16;                                       \
      bfv[nf] = *(const bf16x8*)(Bb + r * 32 + ((quad ^ ((r >> 1) & 3)) << 3)); \
    }                                                                        \
    STAGE; VMA;                                                              \
    PH_TAIL(0)                                                               \
  } while (0)

#define PH_L_B(BB_, STAGE, VMA) do {                                         \
    const ushort* Bb = (BB_);                                                \
    _Pragma("unroll")                                                        \
    for (int nf = 0; nf < 2; ++nf) {                                         \
      int r = wn * 64 + 32 + nf * 16 + m16;                                  \
      bfv[nf] = *(const bf16x8*)(Bb + r * 32 + ((quad ^ ((r >> 1) & 3)) << 3)); \
    }                                                                        \
    STAGE; VMA;                                                              \
    PH_TAIL(1)                                                               \
  } while (0)

#define PH_F(TB, KH, STAGE, VMA) \
    PH_F_B(sAB + ((TB) * 2 + (KH)) * 8192, sAB + 32768 + ((TB) * 2 + (KH)) * 8192, STAGE, VMA)
#define PH_L(TB, KH, STAGE, VMA) \
    PH_L_B(sAB + 32768 + ((TB) * 2 + (KH)) * 8192, STAGE, VMA)

// K-loop over 16 K-tiles (DM=1024), verified staging schedule: prologue
// stages 3 half-tiles (VM8 lands tile0.k0), steady state keeps 3 units in
// flight (VM6 at odd phases), drain waits once (VM0) then 3 stage-free tiles.
#define KLOOP_1024                                                           \
  STAGE_A(0, 0, 0); STAGE_B(0, 0, 0);                                        \
  STAGE_A(0, 1, 0); STAGE_B(0, 1, 0);                                        \
  STAGE_A(1, 0, 1); STAGE_B(1, 0, 1);                                        \
  VM8;                                                                       \
  __builtin_amdgcn_s_barrier();                                              \
  _Pragma("unroll 1")                                                        \
  for (int i = 0; i < 7; ++i) {                                              \
    const int t1 = 2 * i + 1, t2 = 2 * i + 2, t3 = 2 * i + 3;                \
    PH_F(0, 0, STAGE_A(t1, 1, 1), NOPS);                                     \
    PH_L(0, 0, STAGE_B(t1, 1, 1), VM6);                                      \
    PH_F(0, 1, STAGE_A(t2, 0, 0), NOPS);                                     \
    PH_L(0, 1, STAGE_B(t2, 0, 0), VM6);                                      \
    PH_F(1, 0, STAGE_A(t2, 1, 0), NOPS);                                     \
    PH_L(1, 0, STAGE_B(t2, 1, 0), VM6);                                      \
    PH_F(1, 1, STAGE_A(t3, 0, 1), NOPS);                                     \
    PH_L(1, 1, STAGE_B(t3, 0, 1), VM6);                                      \
  }                                                                          \
  PH_F(0, 0, STAGE_A(15, 1, 1), NOPS);                                       \
  PH_L(0, 0, STAGE_B(15, 1, 1), VM0);                                        \
  _Pragma("unroll 1")                                                        \
  for (int u = 1; u < 4; ++u) {                                              \
    const ushort* AbU = sAB + u * 8192;                                      \
    const ushort* BbU = sAB + 32768 + u * 8192;                              \
    PH_F_B(AbU, BbU, NOPS, NOPS);                                            \
    PH_L_B(BbU, NOPS, NOPS);                                                 \
  }

// ---------------- merged Q + KV projection GEMM: 256x256 tiles, 8-phase ----------------
// blocks 0..255:   Q  = x[hilbert rows] @ Wq^T        -> qhb [16384][1024]
// blocks 256..511: KV = x[dilated rows] @ [Wk;Wv]^T   -> kvb [8192][2048]
// XCD-aware bijective swizzle within each 256-block half.
__global__ __launch_bounds__(512) void gemm_qkv(const ushort* __restrict__ xbf,
                                                const ushort* __restrict__ wqkv,
                                                ushort* __restrict__ qhb,
                                                ushort* __restrict__ kvb,
                                                const int* __restrict__ hmap) {
  __shared__ __align__(16) ushort sAB[65536];  // A @0 (4x8192), B @32768 (4x8192)
  __shared__ int sRow[256];

  const int blk = blockIdx.x;
  const int tid = threadIdx.x;
  const int lane = tid & 63;
  const int wave = tid >> 6;
  const int m16 = lane & 15;
  const int quad = lane >> 4;
  const int wm = wave >> 2;   // 0..1  (M half)
  const int wn = wave & 3;    // 0..3  (N quarter)

  const int j0 = blk & 255;
  const int swz = (j0 & 7) * 32 + (j0 >> 3);    // bijective, same-XCD contiguous

  const ushort* Bmat; ushort* C; int row0, col0, N;
  if (blk < 256) {
    row0 = (swz >> 2) * 256; col0 = (swz & 3) * 256;
    Bmat = wqkv; C = qhb; N = DM;
  } else {
    row0 = (swz >> 3) * 256; col0 = (swz & 7) * 256;
    Bmat = wqkv + (size_t)DM * DM; C = kvb; N = KVLD;
  }

  if (tid < 256) {
    int m = row0 + tid, xrow;
    if (blk < 256) {                     // hilbert-ordered Q rows
      int b = m >> 12, p = m & 4095;
      xrow = (b << 12) + hmap[p];
    } else {                             // compact dilated key rows
      int b = m >> 11, idx = m & 2047;
      int ss = idx >> 6, tt = idx & 63;
      xrow = (b << 12) + hmap[ss * SEGSZ + 2 * tt];
    }
    sRow[tid] = xrow;
  }
  __syncthreads();

  // staging: flat 16B chunk f within a unit; row = f>>2, swizzled col slot =
  // (f&3) ^ ((f>>3)&3).  Involution; read side applies the same XOR.
  const int f0 = wave * 64 + lane, f1 = 512 + f0;
  const int r0 = f0 >> 2, c0 = (f0 & 3) ^ ((f0 >> 3) & 3);
  const int r1 = f1 >> 2, c1 = (f1 & 3) ^ ((f1 >> 3) & 3);
  const ushort* pA0 = xbf + (size_t)sRow[r0] * DM + c0 * 8;
  const ushort* pA1 = xbf + (size_t)sRow[r1] * DM + c1 * 8;
  const ushort* pB0 = Bmat + (size_t)(col0 + r0) * DM + c0 * 8;
  const ushort* pB1 = Bmat + (size_t)(col0 + r1) * DM + c1 * 8;

  f32x4 acc[8][4] = {};
  bf16x8 af[8], bfv[2];

  KLOOP_1024

  // C/D layout: col = lane&15, row = (lane>>4)*4 + r
#pragma unroll
  for (int mf = 0; mf < 8; ++mf)
#pragma unroll
    for (int rr = 0; rr < 4; ++rr) {
      int row = row0 + wm * 128 + mf * 16 + quad * 4 + rr;
#pragma unroll
      for (int nf = 0; nf < 4; ++nf)
        C[(size_t)row * N + col0 + wn * 64 + nf * 16 + m16] = f2bf(acc[mf][nf][rr]);
    }
}

// ---------------- out-projection GEMM: 256x256 tiles, 8-phase, fp32 out ----------------
// out[m][n] = sum_k attn[m,k] * Wout[n,k];  grid 256 = 64 row-tiles x 4 col-tiles.
__global__ __launch_bounds__(512) void gemm_out(const ushort* __restrict__ A,
                                                const ushort* __restrict__ Bmat,
                                                float* __restrict__ C) {
  __shared__ __align__(16) ushort sAB[65536];

  const int tid = threadIdx.x;
  const int lane = tid & 63;
  const int wave = tid >> 6;
  const int m16 = lane & 15;
  const int quad = lane >> 4;
  const int wm = wave >> 2;
  const int wn = wave & 3;

  const int j0 = blockIdx.x;
  const int swz = (j0 & 7) * 32 + (j0 >> 3);    // XCD swizzle
  const int row0 = (swz >> 2) * 256;
  const int col0 = (swz & 3) * 256;

  const int f0 = wave * 64 + lane, f1 = 512 + f0;
  const int r0 = f0 >> 2, c0 = (f0 & 3) ^ ((f0 >> 3) & 3);
  const int r1 = f1 >> 2, c1 = (f1 & 3) ^ ((f1 >> 3) & 3);
  const ushort* pA0 = A + (size_t)(row0 + r0) * DM + c0 * 8;
  const ushort* pA1 = A + (size_t)(row0 + r1) * DM + c1 * 8;
  const ushort* pB0 = Bmat + (size_t)(col0 + r0) * DM + c0 * 8;
  const ushort* pB1 = Bmat + (size_t)(col0 + r1) * DM + c1 * 8;

  f32x4 acc[8][4] = {};
  bf16x8 af[8], bfv[2];

  KLOOP_1024

#pragma unroll
  for (int mf = 0; mf < 8; ++mf)
#pragma unroll
    for (int rr = 0; rr < 4; ++rr) {
      int row = row0 + wm * 128 + mf * 16 + quad * 4 + rr;
#pragma unroll
      for (int nf = 0; nf < 4; ++nf)
        C[(size_t)row * DM + col0 + wn * 64 + nf * 16 + m16] = acc[mf][nf][rr];
    }
}

#undef KLOOP_1024
#undef PH_F
#undef PH_L
#undef PH_F_B
#undef PH_L_B
#undef PH_TAIL
#undef STAGE_A
#undef STAGE_B
#undef VM6
#undef VM8
#undef VM0
#undef NOPS

// ---------------- fused hilbert attention (compact inputs, MFMA) ----------------
// one workgroup (256 thr = 4 waves) per (b,h,s): 128 queries x 64 dilated keys.
__global__ __launch_bounds__(256) void attn_kernel(const ushort* __restrict__ qh,
                                                   const ushort* __restrict__ kv,
                                                   ushort* __restrict__ out) {
  __shared__ __align__(16) ushort sQW[128 * 72];  // Q [q][d]; reused for W [q][t]
  __shared__ __align__(16) ushort sK[64 * 72];    // [t][d]
  __shared__ __align__(16) ushort sVT[64 * 72];   // [d][t]
  __shared__ float sCmaxW[4 * 64];
  __shared__ float sDen[128];

  const int bid = blockIdx.x;
  const int s  = bid & 31;
  const int h  = (bid >> 5) & 15;
  const int b  = bid >> 9;
  const int tid = threadIdx.x;
  const int lane = tid & 63;
  const int wave = tid >> 6;
  const int m16 = lane & 15;
  const int quad = lane >> 4;
  const int qb = wave * 32;
  const int hb = wave >> 1;

  // ---- stage Q (128 rows), K + V^T (64 rows) — all coalesced ----
  {
    const int qr = tid >> 1;
    const int qc = (tid & 1) * 32;
    const ushort* qrow = qh + (size_t)(b * MM + s * SEGSZ + qr) * DM + h * HDIM + qc;
    *(uint4*)(sQW + qr * 72 + qc)      = ((const uint4*)qrow)[0];
    *(uint4*)(sQW + qr * 72 + qc + 8)  = ((const uint4*)qrow)[1];
    *(uint4*)(sQW + qr * 72 + qc + 16) = ((const uint4*)qrow)[2];
    *(uint4*)(sQW + qr * 72 + qc + 24) = ((const uint4*)qrow)[3];

    const int r = tid >> 2;
    const int c = (tid & 3) * 16;
    const ushort* krow = kv + (size_t)(b * (MM/2) + s * 64 + r) * KVLD + h * HDIM + c;
    const ushort* vrow = krow + DM;
    *(uint4*)(sK + r * 72 + c)     = ((const uint4*)krow)[0];
    *(uint4*)(sK + r * 72 + c + 8) = ((const uint4*)krow)[1];
    ushort vv[16];
    *(uint4*)(vv)     = ((const uint4*)vrow)[0];
    *(uint4*)(vv + 8) = ((const uint4*)vrow)[1];
#pragma unroll
    for (int u = 0; u < 16; ++u) sVT[(c + u) * 72 + r] = vv[u];
  }
  __syncthreads();

  // ---- S = (Q K^T) * SCALE ----
  f32x4 sc[2][4];
  {
    bf16x8 aq[2][2], bk[4][2];
#pragma unroll
    for (int ks = 0; ks < 2; ++ks) {
#pragma unroll
      for (int ib = 0; ib < 2; ++ib)
        aq[ib][ks] = *(const bf16x8*)(sQW + (qb + ib * 16 + m16) * 72 + ks * 32 + quad * 8);
#pragma unroll
      for (int j = 0; j < 4; ++j)
        bk[j][ks] = *(const bf16x8*)(sK + (j * 16 + m16) * 72 + ks * 32 + quad * 8);
    }
#pragma unroll
    for (int ib = 0; ib < 2; ++ib)
#pragma unroll
      for (int j = 0; j < 4; ++j) {
        f32x4 a = {};
        a = __builtin_amdgcn_mfma_f32_16x16x32_bf16(aq[ib][0], bk[j][0], a, 0, 0, 0);
        a = __builtin_amdgcn_mfma_f32_16x16x32_bf16(aq[ib][1], bk[j][1], a, 0, 0, 0);
        sc[ib][j] = a * 0.125f;
      }
  }

  // ---- per-key max per 64-query block (faithful quirk) ----
#pragma unroll
  for (int j = 0; j < 4; ++j) {
    float m = -1e30f;
#pragma unroll
    for (int ib = 0; ib < 2; ++ib)
#pragma unroll
      for (int r = 0; r < 4; ++r) m = fmaxf(m, sc[ib][j][r]);
    m = fmaxf(m, __shfl_xor(m, 16));
    m = fmaxf(m, __shfl_xor(m, 32));
    if (quad == 0) sCmaxW[wave * 64 + j * 16 + m16] = m;
  }
  __syncthreads();

  // ---- w = exp(s - c); per-row sums; W -> LDS (alias over dead Q) ----
  {
    float part[2][4] = {};
#pragma unroll
    for (int j = 0; j < 4; ++j) {
      const int col = j * 16 + m16;
      float c0 = fmaxf(sCmaxW[hb * 128 + col], sCmaxW[hb * 128 + 64 + col]);
#pragma unroll
      for (int ib = 0; ib < 2; ++ib)
#pragma unroll
        for (int r = 0; r < 4; ++r) {
          float ww = __expf(sc[ib][j][r] - c0);
          sc[ib][j][r] = ww;
          part[ib][r] += ww;
        }
    }
#pragma unroll
    for (int ib = 0; ib < 2; ++ib)
#pragma unroll
      for (int r = 0; r < 4; ++r) {
        float p = part[ib][r];
        p += __shfl_xor(p, 1); p += __shfl_xor(p, 2);
        p += __shfl_xor(p, 4); p += __shfl_xor(p, 8);
        if (m16 == 0) sDen[qb + ib * 16 + quad * 4 + r] = p;
      }
#pragma unroll
    for (int ib = 0; ib < 2; ++ib)
#pragma unroll
      for (int j = 0; j < 4; ++j)
#pragma unroll
        for (int r = 0; r < 4; ++r)
          sQW[(qb + ib * 16 + quad * 4 + r) * 72 + j * 16 + m16] = f2bf(sc[ib][j][r]);
  }
  __syncthreads();

  // ---- O = W @ V via MFMA ----
  f32x4 o[2][4] = {};
  {
    bf16x8 aw[2][2], bv[4][2];
#pragma unroll
    for (int ks = 0; ks < 2; ++ks) {
#pragma unroll
      for (int ib = 0; ib < 2; ++ib)
        aw[ib][ks] = *(const bf16x8*)(sQW + (qb + ib * 16 + m16) * 72 + ks * 32 + quad * 8);
#pragma unroll
      for (int j = 0; j < 4; ++j)
        bv[j][ks] = *(const bf16x8*)(sVT + (j * 16 + m16) * 72 + ks * 32 + quad * 8);
    }
#pragma unroll
    for (int ib = 0; ib < 2; ++ib)
#pragma unroll
      for (int j = 0; j < 4; ++j) {
        o[ib][j] = __builtin_amdgcn_mfma_f32_16x16x32_bf16(aw[ib][0], bv[j][0], o[ib][j], 0, 0, 0);
        o[ib][j] = __builtin_amdgcn_mfma_f32_16x16x32_bf16(aw[ib][1], bv[j][1], o[ib][j], 0, 0, 0);
      }
  }

  // ---- divide by den, store at LINEAR positions ----
#pragma unroll
  for (int ib = 0; ib < 2; ++ib)
#pragma unroll
    for (int r = 0; r < 4; ++r) {
      const int lrow = qb + ib * 16 + quad * 4 + r;
      float rd = 1.0f / (1e-10f + sDen[lrow]);
      ushort* op = out + (size_t)(b * MM + s * SEGSZ + lrow) * DM + h * HDIM + m16;
#pragma unroll
      for (int j = 0; j < 4; ++j)
        op[j * 16] = f2bf(o[ib][j][r] * rd);
    }
}

// ---------------- launch ----------------
extern "C" void kernel_launch(void* const* d_in, const int* in_sizes, int n_in,
                              void* d_out, int out_size, void* d_ws, size_t ws_size,
                              hipStream_t stream) {
  const float* x    = (const float*)d_in[0];
  const float* wqkv = (const float*)d_in[1];
  const float* wout = (const float*)d_in[2];
  const int*   hmap = (const int*)d_in[3];
  float* outp = (float*)d_out;

  ushort* xbf    = (ushort*)d_ws;                          // ROWS*DM
  ushort* wqkvbf = xbf + (size_t)ROWS * DM;                // QKVC*DM
  ushort* woutbf = wqkvbf + (size_t)QKVC * DM;             // DM*DM
  ushort* qhb    = woutbf + (size_t)DM * DM;               // ROWS*DM (hilbert-ordered Q)
  ushort* kvb    = qhb + (size_t)ROWS * DM;                // KVROWS*KVLD (compact K|V)
  ushort* attn   = kvb + (size_t)KVROWS * KVLD;            // ROWS*DM

  cvt_all<<<(NX4 + NW14 + NW24 + 255) / 256, 256, 0, stream>>>(
      (const float4*)x, (const float4*)wqkv, (const float4*)wout,
      (ushort4*)xbf, (ushort4*)wqkvbf, (ushort4*)woutbf);

  // Q + KV projections in one dispatch (512 blocks x 512 thr, 256^2 8-phase)
  gemm_qkv<<<512, 512, 0, stream>>>(xbf, wqkvbf, qhb, kvb, hmap);

  // fused hilbert attention (compact, coalesced)
  attn_kernel<<<BB * NH * NSEG, 256, 0, stream>>>(qhb, kvb, attn);

  // out = attn @ Wout^T (fp32 out, 256^2 8-phase, 256 blocks, XCD swizzle)
  gemm_out<<<256, 512, 0, stream>>>(attn, woutbf, outp);
}

// Round 12
// 252.192 us; speedup vs baseline: 1.0468x; 1.0075x over previous
//
#include <hip/hip_runtime.h>
#include <hip/hip_bf16.h>

// Problem constants (B=4, M=4096, DM=1024, H=16, HD=64, SEG=128, DIL=2, BLOCK_M=64)
#define BB 4
#define MM 4096
#define DM 1024
#define NH 16
#define HDIM 64
#define SEGSZ 128
#define NSEG 32
#define ROWS (BB*MM)     // 16384
#define QKVC (3*DM)      // 3072
#define KVROWS (BB*MM/2) // 8192 compact key rows
#define KVLD 2048        // K | V stacked columns
#define NX4  (ROWS*DM/4)     // 4194304
#define NW14 (QKVC*DM/4)     // 786432
#define NW24 (DM*DM/4)       // 262144

typedef __attribute__((ext_vector_type(8))) short bf16x8;
typedef __attribute__((ext_vector_type(4))) float f32x4;

__device__ inline unsigned short f2bf(float f) {
  __hip_bfloat16 h = __float2bfloat16(f);
  return *reinterpret_cast<unsigned short*>(&h);
}

// async global->LDS, 16B per lane; LDS dest = wave-uniform base + lane*16
__device__ __forceinline__ void gld16(const ushort* g, ushort* l) {
  __builtin_amdgcn_global_load_lds(
      (const __attribute__((address_space(1))) unsigned int*)g,
      (__attribute__((address_space(3))) unsigned int*)l,
      16, 0, 0);
}

// ---------------- fused fp32 -> bf16 convert (x | Wqkv | Wout) ----------------
__global__ __launch_bounds__(256) void cvt_all(const float4* __restrict__ x,
                                               const float4* __restrict__ w1,
                                               const float4* __restrict__ w2,
                                               ushort4* __restrict__ xo,
                                               ushort4* __restrict__ w1o,
                                               ushort4* __restrict__ w2o) {
  int i = blockIdx.x * 256 + threadIdx.x;
  const float4* src; ushort4* dst; int off;
  if (i < NX4)              { src = x;  dst = xo;  off = i; }
  else if (i < NX4 + NW14)  { src = w1; dst = w1o; off = i - NX4; }
  else                      { src = w2; dst = w2o; off = i - NX4 - NW14; }
  float4 v = src[off];
  ushort4 o;
  o.x = f2bf(v.x); o.y = f2bf(v.y); o.z = f2bf(v.z); o.w = f2bf(v.w);
  dst[off] = o;
}

// ======================= 256x256 merged-region macro set =======================
// 512 thr = 8 waves (2M x 4N), BM=BN=256, BK=64 in two K-halves.
// LDS 128 KiB: A units (db,kh) of [256][32] bf16 @0, B units @32768 (XOR-swz).
//
// ROUND-12: merged regions — ONE barrier per K-HALF (2/K-tile, was 4).
// Each region: 12 ds_read_b128 (af[8]+bfv[4]) + 4 gld16 stage + vmcnt(4)
// + barrier + 32 MFMA.  Bigger windows let the compiler interleave region
// r+1's independent ds_reads under region r's MFMA block (reads(q+1) have
// no dep on MFMA(q); counted lgkm orders frag consumption — r10 lesson).
// Hazard ledger (re-derived): region r's stage targets the unit read in
// region r-2, consumed in window r-1, sealed by barrier(r-1) before the
// stage issues (WAR ok; gld16 lands after issue, i.e. after that barrier).
// VM4 in region r-1 leaves only the newest 4 loads in flight, so the unit
// reads(r) need is landed; barrier(r-1) publishes it (RAW ok).  Prologue:
// stage t0.k0+t0.k1, VM4 (t0.k0 landed), barrier.  Drain: R(15,k0) VM0.
#define STAGE_AB(T, KH, DB) do {                                             \
    gld16(pA0 + (T) * 64 + (KH) * 32,                                        \
          sAB + ((DB) * 2 + (KH)) * 8192 + wave * 512);                      \
    gld16(pA1 + (T) * 64 + (KH) * 32,                                        \
          sAB + ((DB) * 2 + (KH)) * 8192 + 4096 + wave * 512);               \
    gld16(pB0 + (T) * 64 + (KH) * 32,                                        \
          sAB + 32768 + ((DB) * 2 + (KH)) * 8192 + wave * 512);              \
    gld16(pB1 + (T) * 64 + (KH) * 32,                                        \
          sAB + 32768 + ((DB) * 2 + (KH)) * 8192 + 4096 + wave * 512);       \
  } while (0)
#define VM4 asm volatile("s_waitcnt vmcnt(4)" ::: "memory")
#define VM0 asm volatile("s_waitcnt vmcnt(0)" ::: "memory")
#define NOPS ((void)0)

// merged region: all 12 fragment reads, stage, vm-wait, ONE barrier, 32 MFMA
#define PH_M(TB, KH, STAGE, VMA) do {                                        \
    const ushort* Ab = sAB + ((TB) * 2 + (KH)) * 8192;                       \
    const ushort* Bb = sAB + 32768 + ((TB) * 2 + (KH)) * 8192;               \
    _Pragma("unroll")                                                        \
    for (int mf = 0; mf < 8; ++mf) {                                         \
      int r = wm * 128 + mf * 16 + m16;                                      \
      af[mf] = *(const bf16x8*)(Ab + r * 32 + ((quad ^ ((r >> 1) & 3)) << 3)); \
    }                                                                        \
    _Pragma("unroll")                                                        \
    for (int nf = 0; nf < 4; ++nf) {                                         \
      int r = wn * 64 + nf * 16 + m16;                                       \
      bfv[nf] = *(const bf16x8*)(Bb + r * 32 + ((quad ^ ((r >> 1) & 3)) << 3)); \
    }                                                                        \
    STAGE; VMA;                                                              \
    __builtin_amdgcn_s_barrier();                                            \
    __builtin_amdgcn_s_setprio(1);                                           \
    _Pragma("unroll")                                                        \
    for (int mf = 0; mf < 8; ++mf)                                           \
      _Pragma("unroll")                                                      \
      for (int nf = 0; nf < 4; ++nf)                                         \
        acc[mf][nf] = __builtin_amdgcn_mfma_f32_16x16x32_bf16(               \
            af[mf], bfv[nf], acc[mf][nf], 0, 0, 0);                          \
    __builtin_amdgcn_s_setprio(0);                                           \
  } while (0)

// K-loop over 16 K-tiles (DM=1024), 32 regions/round.
// Region map: R(t,kh) reads unit (t&1,kh), stages (t+1,kh) -> ((t+1)&1,kh).
#define KLOOP_1024                                                           \
  STAGE_AB(0, 0, 0);                                                         \
  STAGE_AB(0, 1, 0);                                                         \
  VM4;                                                                       \
  __builtin_amdgcn_s_barrier();                                              \
  _Pragma("unroll 1")                                                        \
  for (int i = 0; i < 7; ++i) {                                              \
    const int t1 = 2 * i + 1, t2 = 2 * i + 2;                                \
    PH_M(0, 0, STAGE_AB(t1, 0, 1), VM4);                                     \
    PH_M(0, 1, STAGE_AB(t1, 1, 1), VM4);                                     \
    PH_M(1, 0, STAGE_AB(t2, 0, 0), VM4);                                     \
    PH_M(1, 1, STAGE_AB(t2, 1, 0), VM4);                                     \
  }                                                                          \
  PH_M(0, 0, STAGE_AB(15, 0, 1), VM4);                                       \
  PH_M(0, 1, STAGE_AB(15, 1, 1), VM4);                                       \
  PH_M(1, 0, NOPS, VM0);                                                     \
  PH_M(1, 1, NOPS, NOPS);

// ---------------- merged Q + KV projection GEMM: 256x256 tiles ----------------
// blocks 0..255:   Q  = x[hilbert rows] @ Wq^T        -> qhb [16384][1024]
// blocks 256..511: KV = x[dilated rows] @ [Wk;Wv]^T   -> kvb [8192][2048]
// XCD-aware bijective swizzle within each 256-block half.
__global__ __launch_bounds__(512) void gemm_qkv(const ushort* __restrict__ xbf,
                                                const ushort* __restrict__ wqkv,
                                                ushort* __restrict__ qhb,
                                                ushort* __restrict__ kvb,
                                                const int* __restrict__ hmap) {
  __shared__ __align__(16) ushort sAB[65536];  // A @0 (4x8192), B @32768 (4x8192)
  __shared__ int sRow[256];

  const int blk = blockIdx.x;
  const int tid = threadIdx.x;
  const int lane = tid & 63;
  const int wave = tid >> 6;
  const int m16 = lane & 15;
  const int quad = lane >> 4;
  const int wm = wave >> 2;   // 0..1  (M half)
  const int wn = wave & 3;    // 0..3  (N quarter)

  const int j0 = blk & 255;
  const int swz = (j0 & 7) * 32 + (j0 >> 3);    // bijective, same-XCD contiguous

  const ushort* Bmat; ushort* C; int row0, col0, N;
  if (blk < 256) {
    row0 = (swz >> 2) * 256; col0 = (swz & 3) * 256;
    Bmat = wqkv; C = qhb; N = DM;
  } else {
    row0 = (swz >> 3) * 256; col0 = (swz & 7) * 256;
    Bmat = wqkv + (size_t)DM * DM; C = kvb; N = KVLD;
  }

  if (tid < 256) {
    int m = row0 + tid, xrow;
    if (blk < 256) {                     // hilbert-ordered Q rows
      int b = m >> 12, p = m & 4095;
      xrow = (b << 12) + hmap[p];
    } else {                             // compact dilated key rows
      int b = m >> 11, idx = m & 2047;
      int ss = idx >> 6, tt = idx & 63;
      xrow = (b << 12) + hmap[ss * SEGSZ + 2 * tt];
    }
    sRow[tid] = xrow;
  }
  __syncthreads();

  // staging: flat 16B chunk f within a unit; row = f>>2, swizzled col slot =
  // (f&3) ^ ((f>>3)&3).  Involution; read side applies the same XOR.
  const int f0 = wave * 64 + lane, f1 = 512 + f0;
  const int r0 = f0 >> 2, c0 = (f0 & 3) ^ ((f0 >> 3) & 3);
  const int r1 = f1 >> 2, c1 = (f1 & 3) ^ ((f1 >> 3) & 3);
  const ushort* pA0 = xbf + (size_t)sRow[r0] * DM + c0 * 8;
  const ushort* pA1 = xbf + (size_t)sRow[r1] * DM + c1 * 8;
  const ushort* pB0 = Bmat + (size_t)(col0 + r0) * DM + c0 * 8;
  const ushort* pB1 = Bmat + (size_t)(col0 + r1) * DM + c1 * 8;

  f32x4 acc[8][4] = {};
  bf16x8 af[8], bfv[4];

  KLOOP_1024

  // C/D layout: col = lane&15, row = (lane>>4)*4 + r
#pragma unroll
  for (int mf = 0; mf < 8; ++mf)
#pragma unroll
    for (int rr = 0; rr < 4; ++rr) {
      int row = row0 + wm * 128 + mf * 16 + quad * 4 + rr;
#pragma unroll
      for (int nf = 0; nf < 4; ++nf)
        C[(size_t)row * N + col0 + wn * 64 + nf * 16 + m16] = f2bf(acc[mf][nf][rr]);
    }
}

// ---------------- out-projection GEMM: 256x256 tiles, fp32 out ----------------
// out[m][n] = sum_k attn[m,k] * Wout[n,k];  grid 256 = 64 row-tiles x 4 col-tiles.
__global__ __launch_bounds__(512) void gemm_out(const ushort* __restrict__ A,
                                                const ushort* __restrict__ Bmat,
                                                float* __restrict__ C) {
  __shared__ __align__(16) ushort sAB[65536];

  const int tid = threadIdx.x;
  const int lane = tid & 63;
  const int wave = tid >> 6;
  const int m16 = lane & 15;
  const int quad = lane >> 4;
  const int wm = wave >> 2;
  const int wn = wave & 3;

  const int j0 = blockIdx.x;
  const int swz = (j0 & 7) * 32 + (j0 >> 3);    // XCD swizzle
  const int row0 = (swz >> 2) * 256;
  const int col0 = (swz & 3) * 256;

  const int f0 = wave * 64 + lane, f1 = 512 + f0;
  const int r0 = f0 >> 2, c0 = (f0 & 3) ^ ((f0 >> 3) & 3);
  const int r1 = f1 >> 2, c1 = (f1 & 3) ^ ((f1 >> 3) & 3);
  const ushort* pA0 = A + (size_t)(row0 + r0) * DM + c0 * 8;
  const ushort* pA1 = A + (size_t)(row0 + r1) * DM + c1 * 8;
  const ushort* pB0 = Bmat + (size_t)(col0 + r0) * DM + c0 * 8;
  const ushort* pB1 = Bmat + (size_t)(col0 + r1) * DM + c1 * 8;

  f32x4 acc[8][4] = {};
  bf16x8 af[8], bfv[4];

  KLOOP_1024

#pragma unroll
  for (int mf = 0; mf < 8; ++mf)
#pragma unroll
    for (int rr = 0; rr < 4; ++rr) {
      int row = row0 + wm * 128 + mf * 16 + quad * 4 + rr;
#pragma unroll
      for (int nf = 0; nf < 4; ++nf)
        C[(size_t)row * DM + col0 + wn * 64 + nf * 16 + m16] = acc[mf][nf][rr];
    }
}

#undef KLOOP_1024
#undef PH_M
#undef STAGE_AB
#undef VM4
#undef VM0
#undef NOPS

// ---------------- fused hilbert attention (compact inputs, MFMA) ----------------
// one workgroup (256 thr = 4 waves) per (b,h,s): 128 queries x 64 dilated keys.
__global__ __launch_bounds__(256) void attn_kernel(const ushort* __restrict__ qh,
                                                   const ushort* __restrict__ kv,
                                                   ushort* __restrict__ out) {
  __shared__ __align__(16) ushort sQW[128 * 72];  // Q [q][d]; reused for W [q][t]
  __shared__ __align__(16) ushort sK[64 * 72];    // [t][d]
  __shared__ __align__(16) ushort sVT[64 * 72];   // [d][t]
  __shared__ float sCmaxW[4 * 64];
  __shared__ float sDen[128];

  const int bid = blockIdx.x;
  const int s  = bid & 31;
  const int h  = (bid >> 5) & 15;
  const int b  = bid >> 9;
  const int tid = threadIdx.x;
  const int lane = tid & 63;
  const int wave = tid >> 6;
  const int m16 = lane & 15;
  const int quad = lane >> 4;
  const int qb = wave * 32;
  const int hb = wave >> 1;

  // ---- stage Q (128 rows), K + V^T (64 rows) — all coalesced ----
  {
    const int qr = tid >> 1;
    const int qc = (tid & 1) * 32;
    const ushort* qrow = qh + (size_t)(b * MM + s * SEGSZ + qr) * DM + h * HDIM + qc;
    *(uint4*)(sQW + qr * 72 + qc)      = ((const uint4*)qrow)[0];
    *(uint4*)(sQW + qr * 72 + qc + 8)  = ((const uint4*)qrow)[1];
    *(uint4*)(sQW + qr * 72 + qc + 16) = ((const uint4*)qrow)[2];
    *(uint4*)(sQW + qr * 72 + qc + 24) = ((const uint4*)qrow)[3];

    const int r = tid >> 2;
    const int c = (tid & 3) * 16;
    const ushort* krow = kv + (size_t)(b * (MM/2) + s * 64 + r) * KVLD + h * HDIM + c;
    const ushort* vrow = krow + DM;
    *(uint4*)(sK + r * 72 + c)     = ((const uint4*)krow)[0];
    *(uint4*)(sK + r * 72 + c + 8) = ((const uint4*)krow)[1];
    ushort vv[16];
    *(uint4*)(vv)     = ((const uint4*)vrow)[0];
    *(uint4*)(vv + 8) = ((const uint4*)vrow)[1];
#pragma unroll
    for (int u = 0; u < 16; ++u) sVT[(c + u) * 72 + r] = vv[u];
  }
  __syncthreads();

  // ---- S = (Q K^T) * SCALE ----
  f32x4 sc[2][4];
  {
    bf16x8 aq[2][2], bk[4][2];
#pragma unroll
    for (int ks = 0; ks < 2; ++ks) {
#pragma unroll
      for (int ib = 0; ib < 2; ++ib)
        aq[ib][ks] = *(const bf16x8*)(sQW + (qb + ib * 16 + m16) * 72 + ks * 32 + quad * 8);
#pragma unroll
      for (int j = 0; j < 4; ++j)
        bk[j][ks] = *(const bf16x8*)(sK + (j * 16 + m16) * 72 + ks * 32 + quad * 8);
    }
#pragma unroll
    for (int ib = 0; ib < 2; ++ib)
#pragma unroll
      for (int j = 0; j < 4; ++j) {
        f32x4 a = {};
        a = __builtin_amdgcn_mfma_f32_16x16x32_bf16(aq[ib][0], bk[j][0], a, 0, 0, 0);
        a = __builtin_amdgcn_mfma_f32_16x16x32_bf16(aq[ib][1], bk[j][1], a, 0, 0, 0);
        sc[ib][j] = a * 0.125f;
      }
  }

  // ---- per-key max per 64-query block (faithful quirk) ----
#pragma unroll
  for (int j = 0; j < 4; ++j) {
    float m = -1e30f;
#pragma unroll
    for (int ib = 0; ib < 2; ++ib)
#pragma unroll
      for (int r = 0; r < 4; ++r) m = fmaxf(m, sc[ib][j][r]);
    m = fmaxf(m, __shfl_xor(m, 16));
    m = fmaxf(m, __shfl_xor(m, 32));
    if (quad == 0) sCmaxW[wave * 64 + j * 16 + m16] = m;
  }
  __syncthreads();

  // ---- w = exp(s - c); per-row sums; W -> LDS (alias over dead Q) ----
  {
    float part[2][4] = {};
#pragma unroll
    for (int j = 0; j < 4; ++j) {
      const int col = j * 16 + m16;
      float c0 = fmaxf(sCmaxW[hb * 128 + col], sCmaxW[hb * 128 + 64 + col]);
#pragma unroll
      for (int ib = 0; ib < 2; ++ib)
#pragma unroll
        for (int r = 0; r < 4; ++r) {
          float ww = __expf(sc[ib][j][r] - c0);
          sc[ib][j][r] = ww;
          part[ib][r] += ww;
        }
    }
#pragma unroll
    for (int ib = 0; ib < 2; ++ib)
#pragma unroll
      for (int r = 0; r < 4; ++r) {
        float p = part[ib][r];
        p += __shfl_xor(p, 1); p += __shfl_xor(p, 2);
        p += __shfl_xor(p, 4); p += __shfl_xor(p, 8);
        if (m16 == 0) sDen[qb + ib * 16 + quad * 4 + r] = p;
      }
#pragma unroll
    for (int ib = 0; ib < 2; ++ib)
#pragma unroll
      for (int j = 0; j < 4; ++j)
#pragma unroll
        for (int r = 0; r < 4; ++r)
          sQW[(qb + ib * 16 + quad * 4 + r) * 72 + j * 16 + m16] = f2bf(sc[ib][j][r]);
  }
  __syncthreads();

  // ---- O = W @ V via MFMA ----
  f32x4 o[2][4] = {};
  {
    bf16x8 aw[2][2], bv[4][2];
#pragma unroll
    for (int ks = 0; ks < 2; ++ks) {
#pragma unroll
      for (int ib = 0; ib < 2; ++ib)
        aw[ib][ks] = *(const bf16x8*)(sQW + (qb + ib * 16 + m16) * 72 + ks * 32 + quad * 8);
#pragma unroll
      for (int j = 0; j < 4; ++j)
        bv[j][ks] = *(const bf16x8*)(sVT + (j * 16 + m16) * 72 + ks * 32 + quad * 8);
    }
#pragma unroll
    for (int ib = 0; ib < 2; ++ib)
#pragma unroll
      for (int j = 0; j < 4; ++j) {
        o[ib][j] = __builtin_amdgcn_mfma_f32_16x16x32_bf16(aw[ib][0], bv[j][0], o[ib][j], 0, 0, 0);
        o[ib][j] = __builtin_amdgcn_mfma_f32_16x16x32_bf16(aw[ib][1], bv[j][1], o[ib][j], 0, 0, 0);
      }
  }

  // ---- divide by den, store at LINEAR positions ----
#pragma unroll
  for (int ib = 0; ib < 2; ++ib)
#pragma unroll
    for (int r = 0; r < 4; ++r) {
      const int lrow = qb + ib * 16 + quad * 4 + r;
      float rd = 1.0f / (1e-10f + sDen[lrow]);
      ushort* op = out + (size_t)(b * MM + s * SEGSZ + lrow) * DM + h * HDIM + m16;
#pragma unroll
      for (int j = 0; j < 4; ++j)
        op[j * 16] = f2bf(o[ib][j][r] * rd);
    }
}

// ---------------- launch ----------------
extern "C" void kernel_launch(void* const* d_in, const int* in_sizes, int n_in,
                              void* d_out, int out_size, void* d_ws, size_t ws_size,
                              hipStream_t stream) {
  const float* x    = (const float*)d_in[0];
  const float* wqkv = (const float*)d_in[1];
  const float* wout = (const float*)d_in[2];
  const int*   hmap = (const int*)d_in[3];
  float* outp = (float*)d_out;

  ushort* xbf    = (ushort*)d_ws;                          // ROWS*DM
  ushort* wqkvbf = xbf + (size_t)ROWS * DM;                // QKVC*DM
  ushort* woutbf = wqkvbf + (size_t)QKVC * DM;             // DM*DM
  ushort* qhb    = woutbf + (size_t)DM * DM;               // ROWS*DM (hilbert-ordered Q)
  ushort* kvb    = qhb + (size_t)ROWS * DM;                // KVROWS*KVLD (compact K|V)
  ushort* attn   = kvb + (size_t)KVROWS * KVLD;            // ROWS*DM

  cvt_all<<<(NX4 + NW14 + NW24 + 255) / 256, 256, 0, stream>>>(
      (const float4*)x, (const float4*)wqkv, (const float4*)wout,
      (ushort4*)xbf, (ushort4*)wqkvbf, (ushort4*)woutbf);

  // Q + KV projections in one dispatch (512 blocks x 512 thr)
  gemm_qkv<<<512, 512, 0, stream>>>(xbf, wqkvbf, qhb, kvb, hmap);

  // fused hilbert attention (compact, coalesced)
  attn_kernel<<<BB * NH * NSEG, 256, 0, stream>>>(qhb, kvb, attn);

  // out = attn @ Wout^T (fp32 out, 256 blocks, XCD swizzle)
  gemm_out<<<256, 512, 0, stream>>>(attn, woutbf, outp);
}